// Round 6
// baseline (292.453 us; speedup 1.0000x reference)
//
#include <hip/hip_runtime.h>
#include <stdint.h>
#include <math.h>

#define NUM_TOK 8192
#define DM 512
#define NE 8
#define NH 2048
#define MAX_TILES 40   // 256-row tiles: 8192/256 + 8 partials
#define NBLK 32        // routing blocks of 256 tokens

typedef float f32x4 __attribute__((ext_vector_type(4)));
typedef __bf16 bf16x8 __attribute__((ext_vector_type(8)));

// ws layout (bytes)
#define WS_COUNTS   0                 // int[8]
#define WS_OFFSETS  64                // int[8]
#define WS_CTR      96                // int (spin barrier counter)
#define WS_TILE_E   128               // int[40]
#define WS_TILE_R0  416               // int[40]
#define WS_EXP      704               // int[8192]
#define WS_WTOK     33472             // float[8192]
#define WS_PERM     66240             // int[8192]
#define WS_XG       99008             // bf16 (8192+128) x 512; probs overlaid
#define WS_H        8618688           // bf16 (8192+128) x 2048; hist/imp overlaid
#define WS_W1T      42697408          // bf16 [8][2048][512]
#define WS_W2T      59474624          // bf16 [8][512][2048]
// overlays
#define WS_PROBS    WS_XG             // float[8192][8], dead before k_gather writes Xg
#define WS_BHIST    (WS_H + 32768)    // int[32][8], dead before k_ffn1 writes hbuf
#define WS_BIMP     (WS_H + 33792)    // float[32][8]

__device__ __forceinline__ uint16_t f2bf(float f) {
  union { float f; uint32_t u; } c; c.f = f;
  return (uint16_t)((c.u + 0x7FFFu + ((c.u >> 16) & 1u)) >> 16);
}

__device__ __forceinline__ float gelu_fast(float v) {
  float z = 1.5957691216f * v * (1.0f + 0.044715f * v * v);
  float em = __expf(-z);
  return v / (1.0f + em);
}

__device__ __forceinline__ void gload_lds16(const void* g, void* l) {
  __builtin_amdgcn_global_load_lds(
      (const __attribute__((address_space(1))) uint32_t*)g,
      (__attribute__((address_space(3))) uint32_t*)l, 16, 0, 0);
}

#define WAIT_BARRIER(N) asm volatile("s_waitcnt vmcnt(" #N ")\ns_barrier" ::: "memory")
#define RAW_BARRIER()   asm volatile("s_barrier" ::: "memory")

// ---------------- k_prep: fused weight transpose (4096 blocks) + router (2048 blocks) ----
__global__ __launch_bounds__(256) void k_prep(
    const float* __restrict__ w1, const float* __restrict__ w2,
    uint16_t* __restrict__ w1t, uint16_t* __restrict__ w2t,
    const float* __restrict__ x, const float* __restrict__ u,
    const float* __restrict__ rw, const float* __restrict__ rb,
    int* __restrict__ expert_of, float* __restrict__ wtok,
    float* __restrict__ probs, int* __restrict__ ctr)
{
  __shared__ float T[64][65];
  int bid = blockIdx.x;

  if (bid == 0 && threadIdx.x == 0)
    __hip_atomic_store(ctr, 0, __ATOMIC_RELAXED, __HIP_MEMORY_SCOPE_AGENT);

  if (bid < 2048) {
    // ---- router: one wave per token, fp64, NO atomics ----
    int wv = threadIdx.x >> 6, lane = threadIdx.x & 63;
    int t = bid * 4 + wv;

    const float4* xr = (const float4*)(x + (size_t)t * DM + lane * 8);
    float4 xa = xr[0], xb = xr[1];
    float xs[8] = {xa.x, xa.y, xa.z, xa.w, xb.x, xb.y, xb.z, xb.w};

    double acc[NE];
    #pragma unroll
    for (int e = 0; e < NE; ++e) acc[e] = 0.0;
    #pragma unroll
    for (int j = 0; j < 8; ++j) {
      const float4* rr = (const float4*)(rw + (size_t)(lane * 8 + j) * NE);
      float4 r0 = rr[0], r1 = rr[1];
      double xv = (double)xs[j];
      acc[0] += xv * (double)r0.x; acc[1] += xv * (double)r0.y;
      acc[2] += xv * (double)r0.z; acc[3] += xv * (double)r0.w;
      acc[4] += xv * (double)r1.x; acc[5] += xv * (double)r1.y;
      acc[6] += xv * (double)r1.z; acc[7] += xv * (double)r1.w;
    }
    #pragma unroll
    for (int m = 1; m < 64; m <<= 1) {
      #pragma unroll
      for (int e = 0; e < NE; ++e) acc[e] += __shfl_xor(acc[e], m, 64);
    }
    double lg[NE];
    #pragma unroll
    for (int e = 0; e < NE; ++e) lg[e] = acc[e] + (double)rb[e];

    int le = lane & 7;
    double lgE = le == 0 ? lg[0] : le == 1 ? lg[1] : le == 2 ? lg[2] : le == 3 ? lg[3]
               : le == 4 ? lg[4] : le == 5 ? lg[5] : le == 6 ? lg[6] : lg[7];

    double yE = -1e300;
    if (lane < 8) {
      double uv = (double)u[(size_t)t * NE + lane];
      double g = -log(-log(uv) + 1e-10);
      yE = lgE + g;
    }
    double ymax = yE;
    #pragma unroll
    for (int m = 1; m < 8; m <<= 1) ymax = fmax(ymax, __shfl_xor(ymax, m, 64));
    double ex = (lane < 8) ? exp(yE - ymax) : 0.0;
    double s = ex;
    #pragma unroll
    for (int m = 1; m < 8; m <<= 1) s += __shfl_xor(s, m, 64);
    double p = 1.0 / s;
    unsigned long long mk = __ballot(lane < 8 && yE == ymax);
    int sel = __ffsll(mk) - 1;

    double lm = lgE;
    #pragma unroll
    for (int m = 1; m < 8; m <<= 1) lm = fmax(lm, __shfl_xor(lm, m, 64));
    double pr = exp(lgE - lm);
    double ssum = pr;
    #pragma unroll
    for (int m = 1; m < 8; m <<= 1) ssum += __shfl_xor(ssum, m, 64);

    if (lane < 8) probs[(size_t)t * NE + lane] = (float)(pr / ssum);
    if (lane == 0) {
      expert_of[t] = sel;
      wtok[t] = (float)((1.0 - p) + p);
    }
  } else {
    // ---- transpose+convert: [e][K][N] f32 -> [e][N][K] bf16 ----
    int id = bid - 2048;              // 0..4095
    const float* src; uint16_t* dst; int K, N, nx, rid;
    if (id < 2048) { src = w1; dst = w1t; K = DM; N = NH; nx = NH / 64; rid = id; }
    else           { src = w2; dst = w2t; K = NH; N = DM; nx = DM / 64; rid = id - 2048; }
    int e = rid >> 8;
    int r = rid & 255;
    int n0 = (r % nx) * 64, k0 = (r / nx) * 64;
    const float* sp = src + (size_t)e * K * N;
    uint16_t* d = dst + (size_t)e * K * N;
    int tid = threadIdx.x;
    int tr = tid >> 4;
    int tc = (tid & 15) * 4;
    #pragma unroll
    for (int p = 0; p < 4; ++p) {
      int k = tr + p * 16;
      float4 v = *(const float4*)(sp + (size_t)(k0 + k) * N + n0 + tc);
      T[k][tc] = v.x; T[k][tc + 1] = v.y; T[k][tc + 2] = v.z; T[k][tc + 3] = v.w;
    }
    __syncthreads();
    #pragma unroll
    for (int p = 0; p < 2; ++p) {
      int slot = p * 256 + tid;
      int n = slot >> 3;
      int c = (slot & 7) * 8;
      uint16_t tmp[8];
      #pragma unroll
      for (int j = 0; j < 8; ++j) tmp[j] = f2bf(T[c + j][n]);
      *(uint4*)(d + (size_t)(n0 + n) * K + k0 + c) = *(uint4*)tmp;
    }
  }
}

// ---------------- k_route2: fused postroute + offsets + scatter (32 blocks) ----------------
__global__ __launch_bounds__(256) void k_route2(
    const int* __restrict__ expert_of, const float* __restrict__ probs,
    int* __restrict__ block_hist, float* __restrict__ block_imp,
    int* __restrict__ ctr,
    int* __restrict__ counts, int* __restrict__ offsets,
    float* __restrict__ aux_out, int* __restrict__ tile_e, int* __restrict__ tile_r0,
    int* __restrict__ perm)
{
  __shared__ int whist[4][8];
  __shared__ float wimp[4][8];
  __shared__ int sh[NBLK * 8];
  __shared__ float shf[NBLK * 8];
  __shared__ int scnt[8], soff[8], sbase[8];
  __shared__ float ssum[8];

  int tid = threadIdx.x, lane = tid & 63, wid = tid >> 6;
  int b = blockIdx.x;
  int t = b * 256 + tid;
  int sel = expert_of[t];

  int cnt[8]; int lrank = 0;
  unsigned long long below = (1ull << lane) - 1ull;
  #pragma unroll
  for (int e = 0; e < 8; ++e) {
    unsigned long long m = __ballot(sel == e);
    cnt[e] = (int)__popcll(m);
    if (e == sel) lrank = (int)__popcll(m & below);
  }
  if (lane == 0) {
    #pragma unroll
    for (int e = 0; e < 8; ++e) whist[wid][e] = cnt[e];
  }

  const float4* pp = (const float4*)(probs + (size_t)t * NE);
  float4 pa = pp[0], pb = pp[1];
  float ps[8] = {pa.x, pa.y, pa.z, pa.w, pb.x, pb.y, pb.z, pb.w};
  #pragma unroll
  for (int j = 0; j < 8; ++j) {
    float v = ps[j];
    #pragma unroll
    for (int m = 1; m < 64; m <<= 1) v += __shfl_xor(v, m, 64);
    if (lane == 0) wimp[wid][j] = v;
  }
  __syncthreads();

  if (tid < 8) {
    int c = whist[0][tid] + whist[1][tid] + whist[2][tid] + whist[3][tid];
    __hip_atomic_store(&block_hist[b * 8 + tid], c, __ATOMIC_RELAXED, __HIP_MEMORY_SCOPE_AGENT);
    float sv = wimp[0][tid] + wimp[1][tid] + wimp[2][tid] + wimp[3][tid];
    __hip_atomic_store(&block_imp[b * 8 + tid], sv, __ATOMIC_RELAXED, __HIP_MEMORY_SCOPE_AGENT);
  }
  __syncthreads();

  if (tid == 0) {
    __hip_atomic_fetch_add(ctr, 1, __ATOMIC_RELEASE, __HIP_MEMORY_SCOPE_AGENT);
    while (__hip_atomic_load(ctr, __ATOMIC_ACQUIRE, __HIP_MEMORY_SCOPE_AGENT) < NBLK)
      __builtin_amdgcn_s_sleep(16);
  }
  __syncthreads();

  sh[tid]  = __hip_atomic_load(&block_hist[tid], __ATOMIC_RELAXED, __HIP_MEMORY_SCOPE_AGENT);
  shf[tid] = __hip_atomic_load(&block_imp[tid], __ATOMIC_RELAXED, __HIP_MEMORY_SCOPE_AGENT);
  __syncthreads();

  if (tid < 8) {
    int c = 0; float s = 0.0f;
    #pragma unroll
    for (int bb = 0; bb < NBLK; ++bb) { c += sh[bb * 8 + tid]; s += shf[bb * 8 + tid]; }
    scnt[tid] = c; ssum[tid] = s;
  }
  __syncthreads();
  if (tid < 8) {
    int o = 0;
    for (int e = 0; e < tid; ++e) o += scnt[e];
    soff[tid] = o;
    int run = o;
    for (int bp = 0; bp < b; ++bp) run += sh[bp * 8 + tid];
    sbase[tid] = run;
    if (b == 0) { counts[tid] = scnt[tid]; offsets[tid] = o; }
  }
  __syncthreads();

  if (b == 0 && tid == 0) {
    float a = 0.0f;
    #pragma unroll
    for (int e = 0; e < NE; ++e) {
      float dv = ssum[e] / 8192.0f - 0.125f;
      a += dv * dv;
    }
    aux_out[0] = a / 8.0f;
    int nt = 0;
    for (int e = 0; e < NE; ++e) {
      int ntile = (scnt[e] + 255) >> 8;      // 256-row tiles
      for (int j = 0; j < ntile; ++j) { tile_e[nt] = e; tile_r0[nt] = soff[e] + j * 256; ++nt; }
    }
    for (int i = nt; i < MAX_TILES; ++i) { tile_e[i] = -1; tile_r0[i] = 0; }
  }

  int base = 0;
  #pragma unroll
  for (int w = 0; w < 4; ++w) if (w < wid) base += whist[w][sel];
  perm[sbase[sel] + base + lrank] = t;
}

// ---------------- gather x rows into sorted bf16 Xg ----------------
__global__ __launch_bounds__(64) void k_gather(
    const float* __restrict__ x, const int* __restrict__ perm, uint16_t* __restrict__ Xg)
{
  int r = blockIdx.x;
  int lane = threadIdx.x;
  int t = perm[r];
  const float4* src = (const float4*)(x + (size_t)t * DM);
  float4 a = src[lane * 2];
  float4 b = src[lane * 2 + 1];
  uint32_t p0 = (uint32_t)f2bf(a.x) | ((uint32_t)f2bf(a.y) << 16);
  uint32_t p1 = (uint32_t)f2bf(a.z) | ((uint32_t)f2bf(a.w) << 16);
  uint32_t p2 = (uint32_t)f2bf(b.x) | ((uint32_t)f2bf(b.y) << 16);
  uint32_t p3 = (uint32_t)f2bf(b.z) | ((uint32_t)f2bf(b.w) << 16);
  uint4 v = make_uint4(p0, p1, p2, p3);
  ((uint4*)(Xg + (size_t)r * DM))[lane] = v;
}

// ==================== FFN kernels: BM=256 BN=128 BK=64, 8 waves (2Mx4N), ====
// 3 LDS buffers (144 KiB), fine 4-phase interleave per BK-tile, counted
// vmcnt(6) at tile entry (next tile's 6 loads stay in flight), setprio
// around each MFMA cluster. Per-wave output 128x32, acc[8][2].

#define ISS_A01(AS, B) { gload_lds16(ga[0], AS[B] + loa[0]); ga[0] += 64; \
                         gload_lds16(ga[1], AS[B] + loa[1]); ga[1] += 64; }
#define ISS_A23(AS, B) { gload_lds16(ga[2], AS[B] + loa[2]); ga[2] += 64; \
                         gload_lds16(ga[3], AS[B] + loa[3]); ga[3] += 64; }
#define ISS_B01(BS, B) { gload_lds16(gb[0], BS[B] + lob[0]); gb[0] += 64; \
                         gload_lds16(gb[1], BS[B] + lob[1]); gb[1] += 64; }

#define FFN_TILE_BODY(AS, BS, KT)                                              \
  for (int t = 0; t < KT; ++t) {                                               \
    if (t < KT - 1) WAIT_BARRIER(6); else WAIT_BARRIER(0);                     \
    int bsel = t % 3;                                                          \
    const uint16_t* Ab = &AS[bsel][0];                                         \
    const uint16_t* Bb = &BS[bsel][0];                                         \
    int nb = (t + 2) % 3;                                                      \
    bool st = (t < KT - 2);                                                    \
    int xo0 = (quad ^ (l16 & 7)) * 8;                                          \
    int xo1 = ((4 + quad) ^ (l16 & 7)) * 8;                                    \
    /* phase 0: ks0, mi 0-3 (+B ks0) */                                        \
    bf16x8 bb0[2], bb1[2];                                                     \
    _Pragma("unroll")                                                          \
    for (int ni = 0; ni < 2; ++ni)                                             \
      bb0[ni] = *(const bf16x8*)(Bb + (wn * 32 + ni * 16 + l16) * 64 + xo0);   \
    {                                                                          \
      bf16x8 a[4];                                                             \
      _Pragma("unroll")                                                        \
      for (int mi = 0; mi < 4; ++mi)                                           \
        a[mi] = *(const bf16x8*)(Ab + (wm * 128 + mi * 16 + l16) * 64 + xo0);  \
      if (st) ISS_A01(AS, nb);                                                 \
      __builtin_amdgcn_s_setprio(1);                                           \
      _Pragma("unroll")                                                        \
      for (int mi = 0; mi < 4; ++mi)                                           \
        _Pragma("unroll")                                                      \
        for (int ni = 0; ni < 2; ++ni)                                         \
          acc[mi][ni] = __builtin_amdgcn_mfma_f32_16x16x32_bf16(a[mi], bb0[ni], acc[mi][ni], 0, 0, 0); \
      __builtin_amdgcn_s_setprio(0);                                           \
    }                                                                          \
    RAW_BARRIER();                                                             \
    /* phase 1: ks0, mi 4-7 */                                                 \
    {                                                                          \
      bf16x8 a[4];                                                             \
      _Pragma("unroll")                                                        \
      for (int mi = 0; mi < 4; ++mi)                                           \
        a[mi] = *(const bf16x8*)(Ab + (wm * 128 + (mi + 4) * 16 + l16) * 64 + xo0); \
      if (st) ISS_A23(AS, nb);                                                 \
      __builtin_amdgcn_s_setprio(1);                                           \
      _Pragma("unroll")                                                        \
      for (int mi = 0; mi < 4; ++mi)                                           \
        _Pragma("unroll")                                                      \
        for (int ni = 0; ni < 2; ++ni)                                         \
          acc[mi + 4][ni] = __builtin_amdgcn_mfma_f32_16x16x32_bf16(a[mi], bb0[ni], acc[mi + 4][ni], 0, 0, 0); \
      __builtin_amdgcn_s_setprio(0);                                           \
    }                                                                          \
    RAW_BARRIER();                                                             \
    /* phase 2: ks1, mi 0-3 (+B ks1) */                                        \
    _Pragma("unroll")                                                          \
    for (int ni = 0; ni < 2; ++ni)                                             \
      bb1[ni] = *(const bf16x8*)(Bb + (wn * 32 + ni * 16 + l16) * 64 + xo1);   \
    {                                                                          \
      bf16x8 a[4];                                                             \
      _Pragma("unroll")                                                        \
      for (int mi = 0; mi < 4; ++mi)                                           \
        a[mi] = *(const bf16x8*)(Ab + (wm * 128 + mi * 16 + l16) * 64 + xo1);  \
      if (st) ISS_B01(BS, nb);                                                 \
      __builtin_amdgcn_s_setprio(1);                                           \
      _Pragma("unroll")                                                        \
      for (int mi = 0; mi < 4; ++mi)                                           \
        _Pragma("unroll")                                                      \
        for (int ni = 0; ni < 2; ++ni)                                         \
          acc[mi][ni] = __builtin_amdgcn_mfma_f32_16x16x32_bf16(a[mi], bb1[ni], acc[mi][ni], 0, 0, 0); \
      __builtin_amdgcn_s_setprio(0);                                           \
    }                                                                          \
    RAW_BARRIER();                                                             \
    /* phase 3: ks1, mi 4-7 (no issue; next tile-entry barrier closes) */      \
    {                                                                          \
      bf16x8 a[4];                                                             \
      _Pragma("unroll")                                                        \
      for (int mi = 0; mi < 4; ++mi)                                           \
        a[mi] = *(const bf16x8*)(Ab + (wm * 128 + (mi + 4) * 16 + l16) * 64 + xo1); \
      __builtin_amdgcn_s_setprio(1);                                           \
      _Pragma("unroll")                                                        \
      for (int mi = 0; mi < 4; ++mi)                                           \
        _Pragma("unroll")                                                      \
        for (int ni = 0; ni < 2; ++ni)                                         \
          acc[mi + 4][ni] = __builtin_amdgcn_mfma_f32_16x16x32_bf16(a[mi], bb1[ni], acc[mi + 4][ni], 0, 0, 0); \
      __builtin_amdgcn_s_setprio(0);                                           \
    }                                                                          \
  }

// ---------------- layer 1: h = gelu(Xg @ w1t[e]^T + b1[e]) ----------------
__global__ __launch_bounds__(512) void k_ffn1(
    const uint16_t* __restrict__ Xg, const uint16_t* __restrict__ w1t,
    const float* __restrict__ b1,
    const int* __restrict__ offsets, const int* __restrict__ counts,
    const int* __restrict__ tile_e, const int* __restrict__ tile_r0,
    uint16_t* __restrict__ hbuf)
{
  // work = 40 tiles x 16 colblocks = 640 (div 8), XCD-chunked tile-major
  int w = (blockIdx.x & 7) * (640 / 8) + (blockIdx.x >> 3);
  int tile = w >> 4, cb = w & 15;
  int e = tile_e[tile];
  if (e < 0) return;
  int row0 = tile_r0[tile];
  int row_end = offsets[e] + counts[e];
  int n0 = cb * 128;
  const uint16_t* Bt = w1t + (size_t)e * DM * NH;

  __shared__ uint16_t As[3][256 * 64];   // 96 KiB
  __shared__ uint16_t Bs[3][128 * 64];   // 48 KiB

  int tid = threadIdx.x;
  int lane = tid & 63, wid = tid >> 6;
  int wm = wid >> 2, wn = wid & 3;       // 2M x 4N; wave tile 128x32
  int l16 = lane & 15, quad = lane >> 4;
  int lrow = lane >> 3;
  int lsw  = (lane & 7) ^ lrow;

  const uint16_t *ga[4], *gb[2];
  int loa[4], lob[2];
  #pragma unroll
  for (int j = 0; j < 4; ++j) {
    int rbase = wid * 32 + j * 8;        // 8 waves x 32 = 256 rows
    int rr = row0 + rbase + lrow;
    if (rr > NUM_TOK + 127) rr = NUM_TOK + 127;   // clamp inside padded Xg
    ga[j] = Xg + (size_t)rr * DM + lsw * 8;
    loa[j] = rbase * 64;
  }
  #pragma unroll
  for (int j = 0; j < 2; ++j) {
    int rbase = wid * 16 + j * 8;        // 8 waves x 16 = 128 rows
    gb[j] = Bt + (size_t)(n0 + rbase + lrow) * DM + lsw * 8;
    lob[j] = rbase * 64;
  }

  f32x4 acc[8][2] = {};

  // prologue: tiles 0 and 1 (order matters for vmcnt accounting)
  ISS_A01(As, 0); ISS_A23(As, 0); ISS_B01(Bs, 0);
  ISS_A01(As, 1); ISS_A23(As, 1); ISS_B01(Bs, 1);

  FFN_TILE_BODY(As, Bs, 8)

  #pragma unroll
  for (int ni = 0; ni < 2; ++ni) {
    int col = n0 + wn * 32 + ni * 16 + l16;
    float bv = b1[e * NH + col];
    #pragma unroll
    for (int mi = 0; mi < 8; ++mi) {
      int rbase = wm * 128 + mi * 16 + quad * 4;
      #pragma unroll
      for (int r = 0; r < 4; ++r) {
        int grow = row0 + rbase + r;
        if (grow < row_end) {
          float v = acc[mi][ni][r] + bv;
          hbuf[(size_t)grow * NH + col] = f2bf(gelu_fast(v));
        }
      }
    }
  }
}

// ---------------- layer 2: out[token] = (h @ w2t[e]^T + b2[e]) * w_token ----------------
__global__ __launch_bounds__(512) void k_ffn2(
    const uint16_t* __restrict__ hbuf, const uint16_t* __restrict__ w2t,
    const float* __restrict__ b2,
    const int* __restrict__ offsets, const int* __restrict__ counts,
    const int* __restrict__ tile_e, const int* __restrict__ tile_r0,
    const int* __restrict__ perm, const float* __restrict__ wtok,
    float* __restrict__ out)
{
  // work = 40 tiles x 4 colblocks = 160 (div 8)
  int w = (blockIdx.x & 7) * (160 / 8) + (blockIdx.x >> 3);
  int tile = w >> 2, cb = w & 3;
  int e = tile_e[tile];
  if (e < 0) return;
  int row0 = tile_r0[tile];
  int row_end = offsets[e] + counts[e];
  int n0 = cb * 128;
  const uint16_t* Bt = w2t + (size_t)e * NH * DM;

  __shared__ uint16_t As[3][256 * 64];
  __shared__ uint16_t Bs[3][128 * 64];

  int tid = threadIdx.x;
  int lane = tid & 63, wid = tid >> 6;
  int wm = wid >> 2, wn = wid & 3;       // 2M x 4N; wave tile 128x32
  int l16 = lane & 15, quad = lane >> 4;
  int lrow = lane >> 3;
  int lsw  = (lane & 7) ^ lrow;

  const uint16_t *ga[4], *gb[2];
  int loa[4], lob[2];
  #pragma unroll
  for (int j = 0; j < 4; ++j) {
    int rbase = wid * 32 + j * 8;
    int rr = row0 + rbase + lrow;
    if (rr > NUM_TOK + 127) rr = NUM_TOK + 127;   // clamp inside padded hbuf
    ga[j] = hbuf + (size_t)rr * NH + lsw * 8;
    loa[j] = rbase * 64;
  }
  #pragma unroll
  for (int j = 0; j < 2; ++j) {
    int rbase = wid * 16 + j * 8;
    gb[j] = Bt + (size_t)(n0 + rbase + lrow) * NH + lsw * 8;
    lob[j] = rbase * 64;
  }

  f32x4 acc[8][2] = {};

  ISS_A01(As, 0); ISS_A23(As, 0); ISS_B01(Bs, 0);
  ISS_A01(As, 1); ISS_A23(As, 1); ISS_B01(Bs, 1);

  FFN_TILE_BODY(As, Bs, 32)

  #pragma unroll
  for (int ni = 0; ni < 2; ++ni) {
    int col = n0 + wn * 32 + ni * 16 + l16;
    float bv = b2[e * DM + col];
    #pragma unroll
    for (int mi = 0; mi < 8; ++mi) {
      int rbase = wm * 128 + mi * 16 + quad * 4;
      #pragma unroll
      for (int r = 0; r < 4; ++r) {
        int grow = row0 + rbase + r;
        if (grow < row_end) {
          int tk = perm[grow];
          float wt = wtok[tk];
          out[(size_t)tk * DM + col] = (acc[mi][ni][r] + bv) * wt;
        }
      }
    }
  }
}

extern "C" void kernel_launch(void* const* d_in, const int* in_sizes, int n_in,
                              void* d_out, int out_size, void* d_ws, size_t ws_size,
                              hipStream_t stream)
{
  const float* x  = (const float*)d_in[0];
  const float* u  = (const float*)d_in[1];
  const float* rw = (const float*)d_in[2];
  const float* rb = (const float*)d_in[3];
  const float* w1 = (const float*)d_in[4];
  const float* b1 = (const float*)d_in[5];
  const float* w2 = (const float*)d_in[6];
  const float* b2 = (const float*)d_in[7];
  float* out = (float*)d_out;

  char* ws = (char*)d_ws;
  int*      counts     = (int*)(ws + WS_COUNTS);
  int*      offsets    = (int*)(ws + WS_OFFSETS);
  int*      ctr        = (int*)(ws + WS_CTR);
  int*      tile_e     = (int*)(ws + WS_TILE_E);
  int*      tile_r0    = (int*)(ws + WS_TILE_R0);
  int*      expert_of  = (int*)(ws + WS_EXP);
  float*    wtok       = (float*)(ws + WS_WTOK);
  int*      perm       = (int*)(ws + WS_PERM);
  float*    probs      = (float*)(ws + WS_PROBS);
  int*      block_hist = (int*)(ws + WS_BHIST);
  float*    block_imp  = (float*)(ws + WS_BIMP);
  uint16_t* Xg         = (uint16_t*)(ws + WS_XG);
  uint16_t* hbuf       = (uint16_t*)(ws + WS_H);
  uint16_t* w1t        = (uint16_t*)(ws + WS_W1T);
  uint16_t* w2t        = (uint16_t*)(ws + WS_W2T);

  k_prep<<<dim3(6144), 256, 0, stream>>>(w1, w2, w1t, w2t, x, u, rw, rb,
                                         expert_of, wtok, probs, ctr);
  k_route2<<<dim3(NBLK), 256, 0, stream>>>(expert_of, probs, block_hist, block_imp, ctr,
                                           counts, offsets, out + (size_t)NUM_TOK * DM,
                                           tile_e, tile_r0, perm);
  k_gather<<<dim3(NUM_TOK), 64, 0, stream>>>(x, perm, Xg);
  k_ffn1<<<dim3(640), 512, 0, stream>>>(Xg, w1t, b1, offsets, counts, tile_e, tile_r0, hbuf);
  k_ffn2<<<dim3(160), 512, 0, stream>>>(hbuf, w2t, b2, offsets, counts, tile_e, tile_r0, perm, wtok, out);
}

// Round 7
// 250.687 us; speedup vs baseline: 1.1666x; 1.1666x over previous
//
#include <hip/hip_runtime.h>
#include <stdint.h>
#include <math.h>

#define NUM_TOK 8192
#define DM 512
#define NE 8
#define NH 2048
#define MAX_TILES 72
#define NBLK 32        // routing blocks of 256 tokens

typedef float f32x4 __attribute__((ext_vector_type(4)));
typedef __bf16 bf16x8 __attribute__((ext_vector_type(8)));

// ws layout (bytes)
#define WS_COUNTS   0                 // int[8]
#define WS_OFFSETS  64                // int[8]
#define WS_CTR      96                // int (spin barrier counter)
#define WS_TILE_E   128               // int[72]
#define WS_TILE_R0  416               // int[72]
#define WS_EXP      704               // int[8192]
#define WS_WTOK     33472             // float[8192]
#define WS_PERM     66240             // int[8192]
#define WS_XG       99008             // bf16 (8192+128) x 512; probs overlaid
#define WS_H        8618688           // bf16 (8192+128) x 2048; hist/imp overlaid
#define WS_W1T      42697408          // bf16 [8][2048][512]
#define WS_W2T      59474624          // bf16 [8][512][2048]
// overlays
#define WS_PROBS    WS_XG             // float[8192][8], dead before k_gather writes Xg
#define WS_BHIST    (WS_H + 32768)    // int[32][8], dead before k_ffn1 writes hbuf
#define WS_BIMP     (WS_H + 33792)    // float[32][8]

__device__ __forceinline__ uint16_t f2bf(float f) {
  union { float f; uint32_t u; } c; c.f = f;
  return (uint16_t)((c.u + 0x7FFFu + ((c.u >> 16) & 1u)) >> 16);
}

__device__ __forceinline__ float gelu_fast(float v) {
  float z = 1.5957691216f * v * (1.0f + 0.044715f * v * v);
  float em = __expf(-z);
  return v / (1.0f + em);
}

__device__ __forceinline__ void gload_lds16(const void* g, void* l) {
  __builtin_amdgcn_global_load_lds(
      (const __attribute__((address_space(1))) uint32_t*)g,
      (__attribute__((address_space(3))) uint32_t*)l, 16, 0, 0);
}

#define WAIT_BARRIER(N) asm volatile("s_waitcnt vmcnt(" #N ")\ns_barrier" ::: "memory")
#define RAW_BARRIER()   asm volatile("s_barrier" ::: "memory")

// ---------------- k_prep: fused weight transpose (4096 blocks) + router (2048 blocks) ----
__global__ __launch_bounds__(256) void k_prep(
    const float* __restrict__ w1, const float* __restrict__ w2,
    uint16_t* __restrict__ w1t, uint16_t* __restrict__ w2t,
    const float* __restrict__ x, const float* __restrict__ u,
    const float* __restrict__ rw, const float* __restrict__ rb,
    int* __restrict__ expert_of, float* __restrict__ wtok,
    float* __restrict__ probs, int* __restrict__ ctr)
{
  __shared__ float T[64][65];
  int bid = blockIdx.x;

  if (bid == 0 && threadIdx.x == 0)
    __hip_atomic_store(ctr, 0, __ATOMIC_RELAXED, __HIP_MEMORY_SCOPE_AGENT);

  if (bid < 2048) {
    // ---- router: one wave per token, fp64, NO atomics ----
    int wv = threadIdx.x >> 6, lane = threadIdx.x & 63;
    int t = bid * 4 + wv;

    const float4* xr = (const float4*)(x + (size_t)t * DM + lane * 8);
    float4 xa = xr[0], xb = xr[1];
    float xs[8] = {xa.x, xa.y, xa.z, xa.w, xb.x, xb.y, xb.z, xb.w};

    double acc[NE];
    #pragma unroll
    for (int e = 0; e < NE; ++e) acc[e] = 0.0;
    #pragma unroll
    for (int j = 0; j < 8; ++j) {
      const float4* rr = (const float4*)(rw + (size_t)(lane * 8 + j) * NE);
      float4 r0 = rr[0], r1 = rr[1];
      double xv = (double)xs[j];
      acc[0] += xv * (double)r0.x; acc[1] += xv * (double)r0.y;
      acc[2] += xv * (double)r0.z; acc[3] += xv * (double)r0.w;
      acc[4] += xv * (double)r1.x; acc[5] += xv * (double)r1.y;
      acc[6] += xv * (double)r1.z; acc[7] += xv * (double)r1.w;
    }
    #pragma unroll
    for (int m = 1; m < 64; m <<= 1) {
      #pragma unroll
      for (int e = 0; e < NE; ++e) acc[e] += __shfl_xor(acc[e], m, 64);
    }
    double lg[NE];
    #pragma unroll
    for (int e = 0; e < NE; ++e) lg[e] = acc[e] + (double)rb[e];

    int le = lane & 7;
    double lgE = le == 0 ? lg[0] : le == 1 ? lg[1] : le == 2 ? lg[2] : le == 3 ? lg[3]
               : le == 4 ? lg[4] : le == 5 ? lg[5] : le == 6 ? lg[6] : lg[7];

    double yE = -1e300;
    if (lane < 8) {
      double uv = (double)u[(size_t)t * NE + lane];
      double g = -log(-log(uv) + 1e-10);
      yE = lgE + g;
    }
    double ymax = yE;
    #pragma unroll
    for (int m = 1; m < 8; m <<= 1) ymax = fmax(ymax, __shfl_xor(ymax, m, 64));
    double ex = (lane < 8) ? exp(yE - ymax) : 0.0;
    double s = ex;
    #pragma unroll
    for (int m = 1; m < 8; m <<= 1) s += __shfl_xor(s, m, 64);
    double p = 1.0 / s;
    unsigned long long mk = __ballot(lane < 8 && yE == ymax);
    int sel = __ffsll(mk) - 1;

    double lm = lgE;
    #pragma unroll
    for (int m = 1; m < 8; m <<= 1) lm = fmax(lm, __shfl_xor(lm, m, 64));
    double pr = exp(lgE - lm);
    double ssum = pr;
    #pragma unroll
    for (int m = 1; m < 8; m <<= 1) ssum += __shfl_xor(ssum, m, 64);

    if (lane < 8) probs[(size_t)t * NE + lane] = (float)(pr / ssum);
    if (lane == 0) {
      expert_of[t] = sel;
      wtok[t] = (float)((1.0 - p) + p);
    }
  } else {
    // ---- transpose+convert: [e][K][N] f32 -> [e][N][K] bf16 ----
    int id = bid - 2048;              // 0..4095
    const float* src; uint16_t* dst; int K, N, nx, rid;
    if (id < 2048) { src = w1; dst = w1t; K = DM; N = NH; nx = NH / 64; rid = id; }
    else           { src = w2; dst = w2t; K = NH; N = DM; nx = DM / 64; rid = id - 2048; }
    int e = rid >> 8;
    int r = rid & 255;
    int n0 = (r % nx) * 64, k0 = (r / nx) * 64;
    const float* sp = src + (size_t)e * K * N;
    uint16_t* d = dst + (size_t)e * K * N;
    int tid = threadIdx.x;
    int tr = tid >> 4;
    int tc = (tid & 15) * 4;
    #pragma unroll
    for (int p = 0; p < 4; ++p) {
      int k = tr + p * 16;
      float4 v = *(const float4*)(sp + (size_t)(k0 + k) * N + n0 + tc);
      T[k][tc] = v.x; T[k][tc + 1] = v.y; T[k][tc + 2] = v.z; T[k][tc + 3] = v.w;
    }
    __syncthreads();
    #pragma unroll
    for (int p = 0; p < 2; ++p) {
      int slot = p * 256 + tid;
      int n = slot >> 3;
      int c = (slot & 7) * 8;
      uint16_t tmp[8];
      #pragma unroll
      for (int j = 0; j < 8; ++j) tmp[j] = f2bf(T[c + j][n]);
      *(uint4*)(d + (size_t)(n0 + n) * K + k0 + c) = *(uint4*)tmp;
    }
  }
}

// ---------------- k_route2: fused postroute + offsets + scatter (32 blocks) ----------------
__global__ __launch_bounds__(256) void k_route2(
    const int* __restrict__ expert_of, const float* __restrict__ probs,
    int* __restrict__ block_hist, float* __restrict__ block_imp,
    int* __restrict__ ctr,
    int* __restrict__ counts, int* __restrict__ offsets,
    float* __restrict__ aux_out, int* __restrict__ tile_e, int* __restrict__ tile_r0,
    int* __restrict__ perm)
{
  __shared__ int whist[4][8];
  __shared__ float wimp[4][8];
  __shared__ int sh[NBLK * 8];
  __shared__ float shf[NBLK * 8];
  __shared__ int scnt[8], soff[8], sbase[8];
  __shared__ float ssum[8];

  int tid = threadIdx.x, lane = tid & 63, wid = tid >> 6;
  int b = blockIdx.x;
  int t = b * 256 + tid;
  int sel = expert_of[t];

  int cnt[8]; int lrank = 0;
  unsigned long long below = (1ull << lane) - 1ull;
  #pragma unroll
  for (int e = 0; e < 8; ++e) {
    unsigned long long m = __ballot(sel == e);
    cnt[e] = (int)__popcll(m);
    if (e == sel) lrank = (int)__popcll(m & below);
  }
  if (lane == 0) {
    #pragma unroll
    for (int e = 0; e < 8; ++e) whist[wid][e] = cnt[e];
  }

  const float4* pp = (const float4*)(probs + (size_t)t * NE);
  float4 pa = pp[0], pb = pp[1];
  float ps[8] = {pa.x, pa.y, pa.z, pa.w, pb.x, pb.y, pb.z, pb.w};
  #pragma unroll
  for (int j = 0; j < 8; ++j) {
    float v = ps[j];
    #pragma unroll
    for (int m = 1; m < 64; m <<= 1) v += __shfl_xor(v, m, 64);
    if (lane == 0) wimp[wid][j] = v;
  }
  __syncthreads();

  if (tid < 8) {
    int c = whist[0][tid] + whist[1][tid] + whist[2][tid] + whist[3][tid];
    __hip_atomic_store(&block_hist[b * 8 + tid], c, __ATOMIC_RELAXED, __HIP_MEMORY_SCOPE_AGENT);
    float sv = wimp[0][tid] + wimp[1][tid] + wimp[2][tid] + wimp[3][tid];
    __hip_atomic_store(&block_imp[b * 8 + tid], sv, __ATOMIC_RELAXED, __HIP_MEMORY_SCOPE_AGENT);
  }
  __syncthreads();

  if (tid == 0) {
    __hip_atomic_fetch_add(ctr, 1, __ATOMIC_RELEASE, __HIP_MEMORY_SCOPE_AGENT);
    while (__hip_atomic_load(ctr, __ATOMIC_ACQUIRE, __HIP_MEMORY_SCOPE_AGENT) < NBLK)
      __builtin_amdgcn_s_sleep(16);
  }
  __syncthreads();

  sh[tid]  = __hip_atomic_load(&block_hist[tid], __ATOMIC_RELAXED, __HIP_MEMORY_SCOPE_AGENT);
  shf[tid] = __hip_atomic_load(&block_imp[tid], __ATOMIC_RELAXED, __HIP_MEMORY_SCOPE_AGENT);
  __syncthreads();

  if (tid < 8) {
    int c = 0; float s = 0.0f;
    #pragma unroll
    for (int bb = 0; bb < NBLK; ++bb) { c += sh[bb * 8 + tid]; s += shf[bb * 8 + tid]; }
    scnt[tid] = c; ssum[tid] = s;
  }
  __syncthreads();
  if (tid < 8) {
    int o = 0;
    for (int e = 0; e < tid; ++e) o += scnt[e];
    soff[tid] = o;
    int run = o;
    for (int bp = 0; bp < b; ++bp) run += sh[bp * 8 + tid];
    sbase[tid] = run;
    if (b == 0) { counts[tid] = scnt[tid]; offsets[tid] = o; }
  }
  __syncthreads();

  if (b == 0 && tid == 0) {
    float a = 0.0f;
    #pragma unroll
    for (int e = 0; e < NE; ++e) {
      float dv = ssum[e] / 8192.0f - 0.125f;
      a += dv * dv;
    }
    aux_out[0] = a / 8.0f;
    int nt = 0;
    for (int e = 0; e < NE; ++e) {
      int ntile = (scnt[e] + 127) >> 7;
      for (int j = 0; j < ntile; ++j) { tile_e[nt] = e; tile_r0[nt] = soff[e] + j * 128; ++nt; }
    }
    for (int i = nt; i < MAX_TILES; ++i) { tile_e[i] = -1; tile_r0[i] = 0; }
  }

  int base = 0;
  #pragma unroll
  for (int w = 0; w < 4; ++w) if (w < wid) base += whist[w][sel];
  perm[sbase[sel] + base + lrank] = t;
}

// ---------------- gather x rows into sorted bf16 Xg (256-thread blocks, 4 rows each) ----
__global__ __launch_bounds__(256) void k_gather(
    const float* __restrict__ x, const int* __restrict__ perm, uint16_t* __restrict__ Xg)
{
  int r = blockIdx.x * 4 + (threadIdx.x >> 6);
  int lane = threadIdx.x & 63;
  int t = perm[r];
  const float4* src = (const float4*)(x + (size_t)t * DM);
  float4 a = src[lane * 2];
  float4 b = src[lane * 2 + 1];
  uint32_t p0 = (uint32_t)f2bf(a.x) | ((uint32_t)f2bf(a.y) << 16);
  uint32_t p1 = (uint32_t)f2bf(a.z) | ((uint32_t)f2bf(a.w) << 16);
  uint32_t p2 = (uint32_t)f2bf(b.x) | ((uint32_t)f2bf(b.y) << 16);
  uint32_t p3 = (uint32_t)f2bf(b.z) | ((uint32_t)f2bf(b.w) << 16);
  uint4 v = make_uint4(p0, p1, p2, p3);
  ((uint4*)(Xg + (size_t)r * DM))[lane] = v;
}

// ---------------- layer 1: h = gelu(Xg @ w1t[e]^T + b1[e]) ---- (R2/R5-proven) ----
__global__ __launch_bounds__(512) void k_ffn1(
    const uint16_t* __restrict__ Xg, const uint16_t* __restrict__ w1t,
    const float* __restrict__ b1,
    const int* __restrict__ offsets, const int* __restrict__ counts,
    const int* __restrict__ tile_e, const int* __restrict__ tile_r0,
    uint16_t* __restrict__ hbuf)
{
  // nwg = MAX_TILES*16 = 1152, divisible by 8 -> bijective chunk swizzle
  int w = (blockIdx.x & 7) * (MAX_TILES * 16 / 8) + (blockIdx.x >> 3);
  int tile = w >> 4;          // 16 col-blocks per tile
  int cb = w & 15;
  int e = tile_e[tile];
  if (e < 0) return;
  int row0 = tile_r0[tile];
  int row_end = offsets[e] + counts[e];
  int n0 = cb * 128;
  const uint16_t* Bt = w1t + (size_t)e * DM * NH;

  __shared__ uint16_t As[2][128 * 64];
  __shared__ uint16_t Bs[2][128 * 64];

  int tid = threadIdx.x;
  int lane = tid & 63, wid = tid >> 6;       // wid 0..7
  int wm = wid >> 2, wn = wid & 3;           // 2(M) x 4(N); wave tile 64x32
  int l16 = lane & 15, quad = lane >> 4;

  int lrow = lane >> 3;
  int lsw  = (lane & 7) ^ lrow;
  const uint16_t *ga[2], *gb[2];
  int lo[2];
  #pragma unroll
  for (int j = 0; j < 2; ++j) {
    int r = wid * 16 + j * 8;                // wave owns rows [wid*16, wid*16+16)
    ga[j] = Xg + (size_t)(row0 + r + lrow) * DM + lsw * 8;
    gb[j] = Bt + (size_t)(n0 + r + lrow) * DM + lsw * 8;
    lo[j] = r * 64;
  }

  #define FFN1_ISSUE(B) do { \
    _Pragma("unroll") for (int j = 0; j < 2; ++j) { gload_lds16(ga[j], As[B] + lo[j]); ga[j] += 64; } \
    _Pragma("unroll") for (int j = 0; j < 2; ++j) { gload_lds16(gb[j], Bs[B] + lo[j]); gb[j] += 64; } \
  } while (0)

  f32x4 acc[4][2] = {};

  FFN1_ISSUE(0);
  FFN1_ISSUE(1);
  #pragma unroll 2
  for (int k = 0; k < 8; ++k) {
    if (k < 7) WAIT_BARRIER(4); else WAIT_BARRIER(0);
    int b = k & 1;
    const uint16_t* Ab = As[b];
    const uint16_t* Bb = Bs[b];
    #pragma unroll
    for (int ks = 0; ks < 2; ++ks) {
      bf16x8 a[4], bb[2];
      #pragma unroll
      for (int mi = 0; mi < 4; ++mi) {
        int row = wm * 64 + mi * 16 + l16;
        a[mi] = *(const bf16x8*)(Ab + row * 64 + (((ks * 4 + quad) ^ (l16 & 7)) * 8));
      }
      #pragma unroll
      for (int ni = 0; ni < 2; ++ni) {
        int row = wn * 32 + ni * 16 + l16;
        bb[ni] = *(const bf16x8*)(Bb + row * 64 + (((ks * 4 + quad) ^ (l16 & 7)) * 8));
      }
      #pragma unroll
      for (int mi = 0; mi < 4; ++mi)
        #pragma unroll
        for (int ni = 0; ni < 2; ++ni)
          acc[mi][ni] = __builtin_amdgcn_mfma_f32_16x16x32_bf16(a[mi], bb[ni], acc[mi][ni], 0, 0, 0);
    }
    RAW_BARRIER();
    if (k < 6) { if (b) FFN1_ISSUE(1); else FFN1_ISSUE(0); }
  }

  #pragma unroll
  for (int ni = 0; ni < 2; ++ni) {
    int col = n0 + wn * 32 + ni * 16 + l16;
    float bv = b1[e * NH + col];
    #pragma unroll
    for (int mi = 0; mi < 4; ++mi) {
      int rbase = wm * 64 + mi * 16 + quad * 4;
      #pragma unroll
      for (int r = 0; r < 4; ++r) {
        int grow = row0 + rbase + r;
        if (grow < row_end) {
          float v = acc[mi][ni][r] + bv;
          hbuf[(size_t)grow * NH + col] = f2bf(gelu_fast(v));
        }
      }
    }
  }
}

// ---------------- layer 2: out[token] = (h @ w2t[e]^T + b2[e]) * w_token ---- (R2/R5-proven) ----
__global__ __launch_bounds__(512) void k_ffn2(
    const uint16_t* __restrict__ hbuf, const uint16_t* __restrict__ w2t,
    const float* __restrict__ b2,
    const int* __restrict__ offsets, const int* __restrict__ counts,
    const int* __restrict__ tile_e, const int* __restrict__ tile_r0,
    const int* __restrict__ perm, const float* __restrict__ wtok,
    float* __restrict__ out)
{
  // nwg = MAX_TILES*8 = 576, divisible by 8
  int w = (blockIdx.x & 7) * (MAX_TILES * 8 / 8) + (blockIdx.x >> 3);
  int tile = w >> 3;          // 8 col-blocks of 64 per tile
  int cb = w & 7;
  int e = tile_e[tile];
  if (e < 0) return;
  int row0 = tile_r0[tile];
  int row_end = offsets[e] + counts[e];
  int n0 = cb * 64;
  const uint16_t* Bt = w2t + (size_t)e * NH * DM;

  __shared__ uint16_t As[2][128 * 64];
  __shared__ uint16_t Bs[2][64 * 64];

  int tid = threadIdx.x;
  int lane = tid & 63, wid = tid >> 6;       // wid 0..7
  int wm = wid >> 1, wn = wid & 1;           // 4(M) x 2(N); wave tile 32x32
  int l16 = lane & 15, quad = lane >> 4;

  int lrow = lane >> 3;
  int lsw  = (lane & 7) ^ lrow;
  const uint16_t *ga[2], *gb;
  int loa[2], lob;
  #pragma unroll
  for (int j = 0; j < 2; ++j) {
    int r = wid * 16 + j * 8;
    ga[j] = hbuf + (size_t)(row0 + r + lrow) * NH + lsw * 8;
    loa[j] = r * 64;
  }
  {
    int r = wid * 8;                         // 8 waves x 8 rows = 64 B rows
    gb = Bt + (size_t)(n0 + r + lrow) * NH + lsw * 8;
    lob = r * 64;
  }

  #define FFN2_ISSUE(B) do { \
    _Pragma("unroll") for (int j = 0; j < 2; ++j) { gload_lds16(ga[j], As[B] + loa[j]); ga[j] += 64; } \
    gload_lds16(gb, Bs[B] + lob); gb += 64; \
  } while (0)

  f32x4 acc[2][2] = {};

  FFN2_ISSUE(0);
  FFN2_ISSUE(1);
  #pragma unroll 2
  for (int k = 0; k < 32; ++k) {
    if (k < 31) WAIT_BARRIER(3); else WAIT_BARRIER(0);
    int b = k & 1;
    const uint16_t* Ab = As[b];
    const uint16_t* Bb = Bs[b];
    #pragma unroll
    for (int ks = 0; ks < 2; ++ks) {
      bf16x8 a[2], bb[2];
      #pragma unroll
      for (int mi = 0; mi < 2; ++mi) {
        int row = wm * 32 + mi * 16 + l16;
        a[mi] = *(const bf16x8*)(Ab + row * 64 + (((ks * 4 + quad) ^ (l16 & 7)) * 8));
      }
      #pragma unroll
      for (int ni = 0; ni < 2; ++ni) {
        int row = wn * 32 + ni * 16 + l16;
        bb[ni] = *(const bf16x8*)(Bb + row * 64 + (((ks * 4 + quad) ^ (l16 & 7)) * 8));
      }
      #pragma unroll
      for (int mi = 0; mi < 2; ++mi)
        #pragma unroll
        for (int ni = 0; ni < 2; ++ni)
          acc[mi][ni] = __builtin_amdgcn_mfma_f32_16x16x32_bf16(a[mi], bb[ni], acc[mi][ni], 0, 0, 0);
    }
    RAW_BARRIER();
    if (k < 30) { if (b) FFN2_ISSUE(1); else FFN2_ISSUE(0); }
  }

  #pragma unroll
  for (int ni = 0; ni < 2; ++ni) {
    int col = n0 + wn * 32 + ni * 16 + l16;
    float bv = b2[e * DM + col];
    #pragma unroll
    for (int mi = 0; mi < 2; ++mi) {
      int rbase = wm * 32 + mi * 16 + quad * 4;
      #pragma unroll
      for (int r = 0; r < 4; ++r) {
        int grow = row0 + rbase + r;
        if (grow < row_end) {
          int tk = perm[grow];
          float wt = wtok[tk];
          out[(size_t)tk * DM + col] = (acc[mi][ni][r] + bv) * wt;
        }
      }
    }
  }
}

extern "C" void kernel_launch(void* const* d_in, const int* in_sizes, int n_in,
                              void* d_out, int out_size, void* d_ws, size_t ws_size,
                              hipStream_t stream)
{
  const float* x  = (const float*)d_in[0];
  const float* u  = (const float*)d_in[1];
  const float* rw = (const float*)d_in[2];
  const float* rb = (const float*)d_in[3];
  const float* w1 = (const float*)d_in[4];
  const float* b1 = (const float*)d_in[5];
  const float* w2 = (const float*)d_in[6];
  const float* b2 = (const float*)d_in[7];
  float* out = (float*)d_out;

  char* ws = (char*)d_ws;
  int*      counts     = (int*)(ws + WS_COUNTS);
  int*      offsets    = (int*)(ws + WS_OFFSETS);
  int*      ctr        = (int*)(ws + WS_CTR);
  int*      tile_e     = (int*)(ws + WS_TILE_E);
  int*      tile_r0    = (int*)(ws + WS_TILE_R0);
  int*      expert_of  = (int*)(ws + WS_EXP);
  float*    wtok       = (float*)(ws + WS_WTOK);
  int*      perm       = (int*)(ws + WS_PERM);
  float*    probs      = (float*)(ws + WS_PROBS);
  int*      block_hist = (int*)(ws + WS_BHIST);
  float*    block_imp  = (float*)(ws + WS_BIMP);
  uint16_t* Xg         = (uint16_t*)(ws + WS_XG);
  uint16_t* hbuf       = (uint16_t*)(ws + WS_H);
  uint16_t* w1t        = (uint16_t*)(ws + WS_W1T);
  uint16_t* w2t        = (uint16_t*)(ws + WS_W2T);

  k_prep<<<dim3(6144), 256, 0, stream>>>(w1, w2, w1t, w2t, x, u, rw, rb,
                                         expert_of, wtok, probs, ctr);
  k_route2<<<dim3(NBLK), 256, 0, stream>>>(expert_of, probs, block_hist, block_imp, ctr,
                                           counts, offsets, out + (size_t)NUM_TOK * DM,
                                           tile_e, tile_r0, perm);
  k_gather<<<dim3(NUM_TOK / 4), 256, 0, stream>>>(x, perm, Xg);
  k_ffn1<<<dim3(MAX_TILES * 16), 512, 0, stream>>>(Xg, w1t, b1, offsets, counts, tile_e, tile_r0, hbuf);
  k_ffn2<<<dim3(MAX_TILES * 8), 512, 0, stream>>>(hbuf, w2t, b2, offsets, counts, tile_e, tile_r0, perm, wtok, out);
}